// Round 1
// 371.681 us; speedup vs baseline: 1.6048x; 1.6048x over previous
//
#include <hip/hip_runtime.h>

// R4: FIR correlation as band-Toeplitz MFMA GEMM (fp16 operands, fp32 accumulate).
//   out[r, t] = sum_j e[r, j] * g[j - t],  g[k] = h[412-k], e = reflect-extended row.
// Tile: 16 rows x 16 outputs per wave-tile; K-chunks of 32 taps, 14 chunks cover the
// 428-wide j-window (92% efficiency).
//   A (filter Toeplitz, in registers): A_q[m,k] = g[32q + k - m], split hi/lo fp16
//     (sh + sl == h to 2^-22) -> added error is signal fp16 quant only (~2.8e-4 max).
//   B (signal, LDS): B_q[k,n] = e[row n, t0 + 32q + k]; lane reads 8 contiguous fp16
//     = 1 ds_read_b128; row stride 2064 B (16B-slot rotation mod 128 -> <=2-way alias).
//   D: col = lane&15 -> signal row; row = (lane>>4)*4 + reg -> 4 consecutive t
//     -> one dwordx4 store per lane per tile.
// Per 256-output tile: 14 ds_read_b128 + 28 MFMA + 1 store. Expected HBM/LDS co-bound.

#define T_LEN 10000
#define N_H   413
#define SHIFT 206            // (N_H-1)/2
#define TB    576            // outputs per block = 36 tiles of 16
#define SPAN  1024           // staged e-span per block = TB + 448
#define SPANP 1032           // halfs per LDS row (+8 halfs = 16B pad -> stride 2064 B)
#define NQ    14             // K-chunks (x32 taps) per tile
#define NTBLK 18             // ceil(10000 / 576); last block has 208 outputs = 13 tiles

typedef _Float16 v8h   __attribute__((ext_vector_type(8)));
typedef float    v4f   __attribute__((ext_vector_type(4)));
typedef float    f32x2 __attribute__((ext_vector_type(2)));

__global__ __launch_bounds__(256, 3) void FilterBank_20624432955781_kernel(
    const float* __restrict__ x, const float* __restrict__ h, float* __restrict__ out) {
    __shared__ _Float16 lds_e[16][SPANP];     // 33.0 KB staged signal (fp16)
    __shared__ _Float16 gqh[464], gql[464];   // padded reversed filter, hi/lo fp16
                                              // gq[z] = g[z-15] = h[427-z] for z in [15,428)

    const int tid = threadIdx.x;
    const int t0b = blockIdx.x * TB;          // first output of this block
    const int r0  = blockIdx.y * 16;          // first signal row of this block
    const float* __restrict__ xblk = x + (size_t)r0 * T_LEN;

    // ---- stage filter: reversed, zero-padded, split into fp16 hi + lo ----
    for (int z = tid; z < 464; z += 256) {
        const float gv = (z >= 15 && z < 15 + N_H) ? h[427 - z] : 0.0f;
        const _Float16 hi = (_Float16)gv;
        gqh[z] = hi;
        gql[z] = (_Float16)(gv - (float)hi);
    }

    // ---- stage reflect-extended signal e[j], j in [t0b, t0b + SPAN), as fp16 ----
    // 16 rows x 128 groups of 8; thread handles one 8-group: 4x float2 load (8B-aligned,
    // xi0 = j0-206 == 2 mod 8), cvt to fp16, one ds_write_b128.
    for (int gidx = tid; gidx < 16 * (SPAN / 8); gidx += 256) {
        const int rr = gidx >> 7;             // SPAN/8 = 128 groups per row
        const int c8 = gidx & 127;
        const int j0 = t0b + c8 * 8;
        const float* __restrict__ xr = xblk + (size_t)rr * T_LEN;
        float v[8];
        if (j0 >= SHIFT && j0 + 8 <= T_LEN + SHIFT) {           // interior fast path
            const f32x2* xp = (const f32x2*)(xr + (j0 - SHIFT));
            #pragma unroll
            for (int p = 0; p < 4; ++p) { f32x2 t2 = xp[p]; v[2*p] = t2.x; v[2*p+1] = t2.y; }
        } else {                                                // reflect_limited edges
            #pragma unroll
            for (int k = 0; k < 8; ++k) {
                const int j = j0 + k;
                if (j < SHIFT)              v[k] = 2.0f * xr[0] - xr[SHIFT - j];
                else if (j < T_LEN + SHIFT) v[k] = xr[j - SHIFT];
                else                        v[k] = 2.0f * xr[T_LEN - 1] - xr[2 * T_LEN + SHIFT - 2 - j];
                // j can exceed T_LEN+SHIFT+205 only where the filter operand is 0-padded;
                // the mirror index stays in-bounds (j <= 10815 -> idx >= 9389).
            }
        }
        v8h hv;
        #pragma unroll
        for (int k = 0; k < 8; ++k) hv[k] = (_Float16)v[k];
        *(v8h*)&lds_e[rr][c8 * 8] = hv;
    }
    __syncthreads();

    const int l   = tid & 63;
    const int wv  = tid >> 6;
    const int g4  = l >> 4;                   // k-group 0..3 (8 taps each)
    const int r16 = l & 15;                   // A row m / B col n / D col

    // ---- build Toeplitz filter fragments in registers: A_q[m,k] = g[32q + k - m] ----
    // lane l, elem i: z = 32q + (8*g4 + i) - r16 + 15  in [0, 463) -> no bounds checks.
    v8h afh[NQ], afl[NQ];
    #pragma unroll
    for (int q = 0; q < NQ; ++q) {
        const int zb = 32 * q + 8 * g4 - r16 + 15;
        #pragma unroll
        for (int i = 0; i < 8; ++i) { afh[q][i] = gqh[zb + i]; afl[q][i] = gql[zb + i]; }
    }

    // ---- compute: each wave takes tiles tt = wv, wv+4, ... ----
    const int NT = (min(TB, T_LEN - t0b)) >> 4;   // 36 full blocks, 13 tail
    for (int tt = wv; tt < NT; tt += 4) {
        const int trel = tt * 16;
        // B base: lane reads lds_e[r16][trel + 8*g4 + 32*q + i]; q-step = 4 v8h = 64 B,
        // folded into ds_read offset immediates.
        const v8h* __restrict__ bp = (const v8h*)&lds_e[r16][trel + 8 * g4];
        v4f acc0 = {0.f, 0.f, 0.f, 0.f};
        v4f acc1 = {0.f, 0.f, 0.f, 0.f};
        #pragma unroll
        for (int q = 0; q < NQ; ++q) {
            const v8h b = bp[4 * q];
            acc0 = __builtin_amdgcn_mfma_f32_16x16x32_f16(afh[q], b, acc0, 0, 0, 0);
            acc1 = __builtin_amdgcn_mfma_f32_16x16x32_f16(afl[q], b, acc1, 0, 0, 0);
        }
        const v4f acc = acc0 + acc1;
        // D: lane writes out[r0 + r16][t0b + trel + 4*g4 + 0..3] -> 16B-aligned dwordx4.
        float* op = out + (size_t)(r0 + r16) * T_LEN + (t0b + trel + 4 * g4);
        *(v4f*)op = acc;
    }
}

extern "C" void kernel_launch(void* const* d_in, const int* in_sizes, int n_in,
                              void* d_out, int out_size, void* d_ws, size_t ws_size,
                              hipStream_t stream) {
    const float* x = (const float*)d_in[0];   // [64,64,10000] fp32
    const float* h = (const float*)d_in[1];   // [413] fp32
    float* out = (float*)d_out;               // [64,64,10000] fp32
    dim3 grid(NTBLK, 64 * 64 / 16);           // 18 t-blocks x 256 row-blocks
    FilterBank_20624432955781_kernel<<<grid, dim3(256), 0, stream>>>(x, h, out);
}